// Round 4
// baseline (17.911 us; speedup 1.0000x reference)
//
#include <hip/hip_runtime.h>
#include <math.h>

#define HEADS 8
#define BATCH 4
#define SEQ 2048
#define CDIM 32
#define WINDOW 10
#define WSZ 21                       // keys per query row
#define RPB 32                       // query rows per block
#define BAND (RPB + 2 * WINDOW)      // 52 band rows staged in LDS

// DPP cross-lane add (pure VALU). xor1 = quad_perm 0xB1, xor2 = quad_perm
// 0x4E, cross-quad within 8-lane group = row_half_mirror 0x141.
#define DPP_ADD(x, ctrl) \
    ((x) + __int_as_float(__builtin_amdgcn_mov_dpp(__float_as_int(x), (ctrl), 0xF, 0xF, true)))

// 8 lanes per TWO consecutive query rows: each K/V LDS read (1 KB/wave)
// feeds dot products for both rows -> DS-pipe work per row halves vs R2.
__global__ __launch_bounds__(128) void lwin_attn_kernel(
    const float* __restrict__ Q, const float* __restrict__ K,
    const float* __restrict__ V, const float* __restrict__ G,
    const unsigned char* __restrict__ seqMask, float* __restrict__ out)
{
    __shared__ float k_lds[BAND][CDIM];   // 6656 B
    __shared__ float v_lds[BAND][CDIM];   // 6656 B
    __shared__ unsigned int bm_lds[2];

    const int b  = blockIdx.x;
    const int hn = b >> 6;                       // h*BATCH + n
    const int s0 = (b & 63) * RPB;
    const int n  = hn & 3;
    const int h  = hn >> 2;
    const int base_hn = hn * SEQ * CDIM;

    // ---- band invalid mask: one ballot by wave 0 ----
    if (threadIdx.x < 64) {
        const int i  = threadIdx.x;
        const int t  = s0 - WINDOW + i;
        const int tc = min(max(t, 0), SEQ - 1);
        const bool invalid =
            (i < BAND) && ((t < 0) || (t >= SEQ) || (seqMask[n * SEQ + tc] != 0));
        const unsigned long long bmw = __ballot(invalid);
        if (threadIdx.x == 0) {
            bm_lds[0] = (unsigned int)bmw;
            bm_lds[1] = (unsigned int)(bmw >> 32);
        }
    }

    // ---- stage K and V band rows into LDS (coalesced float4) ----
#pragma unroll
    for (int it = 0; it < 7; ++it) {
        const int task = threadIdx.x + it * 128;          // need 832
        if (task < 2 * BAND * 8) {
            const bool isK = task < BAND * 8;
            const int  tt  = isK ? task : task - BAND * 8;
            const int  i   = tt >> 3;
            const int  ch  = (tt & 7) * 4;
            const int  t   = s0 - WINDOW + i;
            const int  tc  = min(max(t, 0), SEQ - 1);
            const float* src = isK ? K : V;
            float*       dst = isK ? &k_lds[0][0] : &v_lds[0][0];
            const float4 val = *(const float4*)&src[base_hn + tc * CDIM + ch];
            *(float4*)&dst[i * CDIM + ch] = val;
        }
    }
    __syncthreads();

    // ---- per-pair compute: 8 lanes per row-pair, 4 channels per lane ----
    const int wv   = threadIdx.x >> 6;           // wave 0..1
    const int lane = threadIdx.x & 63;
    const int grp  = lane >> 3;                  // 0..7
    const int sub  = lane & 7;
    const int c0   = sub * 4;
    const int ra   = wv * 16 + grp * 2;          // local row a (even)
    const int rowa = hn * SEQ + s0 + ra;

    const float scale = 0.17677669529663687f;    // 1/sqrt(32)
    float4 qa = *(const float4*)&Q[rowa * CDIM + c0];
    float4 qb = *(const float4*)&Q[(rowa + 1) * CDIM + c0];
    qa.x *= scale; qa.y *= scale; qa.z *= scale; qa.w *= scale;
    qb.x *= scale; qb.y *= scale; qb.z *= scale; qb.w *= scale;

    const unsigned long long bm =
        ((unsigned long long)bm_lds[1] << 32) | (unsigned long long)bm_lds[0];
    const unsigned int bmA = (unsigned int)(bm >> ra);
    const unsigned int bmB = (unsigned int)(bm >> (ra + 1));

    float sA[WSZ], sB[WSZ];
#pragma unroll
    for (int m = 0; m <= WSZ; ++m) {             // 22 K rows cover both rows
        const float4 k = *(const float4*)&k_lds[ra + m][c0];
        if (m < WSZ) {
            float pa = qa.x * k.x + qa.y * k.y + qa.z * k.z + qa.w * k.w;
            pa = DPP_ADD(pa, 0xB1);
            pa = DPP_ADD(pa, 0x4E);
            pa = DPP_ADD(pa, 0x141);
            sA[m] = ((bmA >> m) & 1u) ? -1e30f : pa;
        }
        if (m >= 1) {
            float pb = qb.x * k.x + qb.y * k.y + qb.z * k.z + qb.w * k.w;
            pb = DPP_ADD(pb, 0xB1);
            pb = DPP_ADD(pb, 0x4E);
            pb = DPP_ADD(pb, 0x141);
            sB[m - 1] = ((bmB >> (m - 1)) & 1u) ? -1e30f : pb;
        }
    }

    // ---- softmax over 21 scores for each row ----
    float mA = -1e30f, mB = -1e30f;
#pragma unroll
    for (int j = 0; j < WSZ; ++j) { mA = fmaxf(mA, sA[j]); mB = fmaxf(mB, sB[j]); }
    float sumA = 0.f, sumB = 0.f;
#pragma unroll
    for (int j = 0; j < WSZ; ++j) {
        const float ea = __expf(sA[j] - mA);
        const float eb = __expf(sB[j] - mB);
        sA[j] = ea; sB[j] = eb;
        sumA += ea; sumB += eb;
    }
    const float invA = 1.0f / sumA;
    const float invB = 1.0f / sumB;

    // ---- PV from LDS (each V row feeds both rows) + gate ----
    float4 accA = make_float4(0.f, 0.f, 0.f, 0.f);
    float4 accB = make_float4(0.f, 0.f, 0.f, 0.f);
#pragma unroll
    for (int m = 0; m <= WSZ; ++m) {
        const float4 v = *(const float4*)&v_lds[ra + m][c0];
        if (m < WSZ) {
            accA.x = fmaf(sA[m], v.x, accA.x);
            accA.y = fmaf(sA[m], v.y, accA.y);
            accA.z = fmaf(sA[m], v.z, accA.z);
            accA.w = fmaf(sA[m], v.w, accA.w);
        }
        if (m >= 1) {
            accB.x = fmaf(sB[m - 1], v.x, accB.x);
            accB.y = fmaf(sB[m - 1], v.y, accB.y);
            accB.z = fmaf(sB[m - 1], v.z, accB.z);
            accB.w = fmaf(sB[m - 1], v.w, accB.w);
        }
    }

    const float4 ga = *(const float4*)&G[rowa * CDIM + c0];
    const float4 gb = *(const float4*)&G[(rowa + 1) * CDIM + c0];
    float4 oa, ob;
    oa.x = accA.x * invA * ga.x;  oa.y = accA.y * invA * ga.y;
    oa.z = accA.z * invA * ga.z;  oa.w = accA.w * invA * ga.w;
    ob.x = accB.x * invB * gb.x;  ob.y = accB.y * invB * gb.y;
    ob.z = accB.z * invB * gb.z;  ob.w = accB.w * invB * gb.w;

    // out[n, s, h, i]
    const int sa = s0 + ra;
    *(float4*)&out[((n * SEQ + sa) * HEADS + h) * CDIM + c0] = oa;
    *(float4*)&out[((n * SEQ + sa + 1) * HEADS + h) * CDIM + c0] = ob;
}

extern "C" void kernel_launch(void* const* d_in, const int* in_sizes, int n_in,
                              void* d_out, int out_size, void* d_ws, size_t ws_size,
                              hipStream_t stream) {
    const float* Q = (const float*)d_in[0];
    const float* K = (const float*)d_in[1];
    const float* V = (const float*)d_in[2];
    const float* G = (const float*)d_in[3];
    const unsigned char* seqMask = (const unsigned char*)d_in[4];
    float* out = (float*)d_out;

    const int blocks = HEADS * BATCH * (SEQ / RPB);   // 2048
    lwin_attn_kernel<<<blocks, 128, 0, stream>>>(Q, K, V, G, seqMask, out);
}